// Round 1
// baseline (9998.347 us; speedup 1.0000x reference)
//
#include <hip/hip_runtime.h>
#include <hip/hip_bf16.h>
#include <math.h>

#define LL 4
#define HH 12
#define EE 768
#define TT 1024
#define VV 50257
#define BB 2
#define MM (BB*TT)      // 2048
#define HD 64
#define EPS 1e-5f
#define SCALE 0.03608439182435161f   // 1/sqrt(768)

// ---------------- embedding ----------------
__global__ __launch_bounds__(256) void k_embed(const int* __restrict__ idx,
                                               const float* __restrict__ wte,
                                               const float* __restrict__ wpe,
                                               float* __restrict__ x) {
    int row = blockIdx.x;            // 0..M-1
    int t = row % TT;
    int tok = idx[row];
    const float* wt = wte + (size_t)tok * EE;
    const float* wp = wpe + (size_t)t * EE;
    float* xr = x + (size_t)row * EE;
    for (int e = threadIdx.x; e < EE; e += 256)
        xr[e] = wt[e] + wp[e];
}

// ---------------- layernorm ----------------
__device__ __forceinline__ float wred_sum(float v) {
    #pragma unroll
    for (int o = 32; o; o >>= 1) v += __shfl_down(v, o);
    return v;
}
__device__ __forceinline__ float wred_max(float v) {
    #pragma unroll
    for (int o = 32; o; o >>= 1) v = fmaxf(v, __shfl_down(v, o));
    return v;
}

__global__ __launch_bounds__(256) void k_ln(const float* __restrict__ x,
                                            const float* __restrict__ w,
                                            const float* __restrict__ b,
                                            float* __restrict__ out) {
    int row = blockIdx.x;
    int tid = threadIdx.x;
    const float* xr = x + (size_t)row * EE;
    float* orow = out + (size_t)row * EE;
    float vals[3];
    float sum = 0.f, sq = 0.f;
    #pragma unroll
    for (int i = 0; i < 3; ++i) {
        float v = xr[tid + i * 256];
        vals[i] = v; sum += v; sq += v * v;
    }
    __shared__ float r1[4], r2[4];
    int lane = tid & 63, wid = tid >> 6;
    sum = wred_sum(sum); sq = wred_sum(sq);
    if (lane == 0) { r1[wid] = sum; r2[wid] = sq; }
    __syncthreads();
    sum = r1[0] + r1[1] + r1[2] + r1[3];
    sq  = r2[0] + r2[1] + r2[2] + r2[3];
    float mu = sum * (1.f / EE);
    float var = sq * (1.f / EE) - mu * mu;
    float rstd = rsqrtf(var + EPS);
    #pragma unroll
    for (int i = 0; i < 3; ++i) {
        int c = tid + i * 256;
        orow[c] = (vals[i] - mu) * rstd * w[c] + b[c];
    }
}

// ---------------- GEMM: C = epi(A @ B + bias [+ resid]) ----------------
// A: [M,K] row-major.  B: [K,N] row-major, or [N,K] if TRANS_B.
// EPI: 0 = none, 1 = tanh-gelu, 2 = add resid (resid is [M,N])
template<bool TRANS_B, int EPI>
__global__ __launch_bounds__(256) void k_gemm(const float* __restrict__ A,
                                              const float* __restrict__ Bm,
                                              const float* __restrict__ bias,
                                              const float* __restrict__ resid,
                                              float* __restrict__ C,
                                              int M, int N, int K) {
    __shared__ float As[16][65];   // [k][m]
    __shared__ float Bs[16][65];   // [k][n]
    int tid = threadIdx.x;
    int tx = tid & 15, ty = tid >> 4;
    int row0 = blockIdx.y * 64, col0 = blockIdx.x * 64;
    float acc[4][4] = {};
    for (int kt = 0; kt < K; kt += 16) {
        #pragma unroll
        for (int l = 0; l < 4; ++l) {
            int e = tid + l * 256;
            int r = e >> 4, c = e & 15;          // r=m-local, c=k-local
            As[c][r] = A[(size_t)(row0 + r) * K + kt + c];
        }
        if (!TRANS_B) {
            #pragma unroll
            for (int l = 0; l < 4; ++l) {
                int e = tid + l * 256;
                int r = e >> 6, c = e & 63;      // r=k-local, c=n-local
                int col = col0 + c;
                Bs[r][c] = (col < N) ? Bm[(size_t)(kt + r) * N + col] : 0.f;
            }
        } else {
            #pragma unroll
            for (int l = 0; l < 4; ++l) {
                int e = tid + l * 256;
                int r = e >> 4, c = e & 15;      // r=n-local, c=k-local
                int col = col0 + r;
                Bs[c][r] = (col < N) ? Bm[(size_t)col * K + kt + c] : 0.f;
            }
        }
        __syncthreads();
        #pragma unroll
        for (int kk = 0; kk < 16; ++kk) {
            float a[4], b[4];
            #pragma unroll
            for (int i = 0; i < 4; ++i) a[i] = As[kk][ty * 4 + i];
            #pragma unroll
            for (int j = 0; j < 4; ++j) b[j] = Bs[kk][tx * 4 + j];
            #pragma unroll
            for (int i = 0; i < 4; ++i)
                #pragma unroll
                for (int j = 0; j < 4; ++j)
                    acc[i][j] = fmaf(a[i], b[j], acc[i][j]);
        }
        __syncthreads();
    }
    #pragma unroll
    for (int i = 0; i < 4; ++i) {
        int row = row0 + ty * 4 + i;
        #pragma unroll
        for (int j = 0; j < 4; ++j) {
            int col = col0 + tx * 4 + j;
            if (col < N) {
                float v = acc[i][j];
                if (bias) v += bias[col];
                if (EPI == 1) {
                    float xx = v;
                    float t = tanhf(0.7978845608028654f * (xx + 0.044715f * xx * xx * xx));
                    v = 0.5f * xx * (1.f + t);
                }
                if (EPI == 2) v += resid[(size_t)row * N + col];
                C[(size_t)row * N + col] = v;
            }
        }
    }
}

// ---------------- attention (flash-style, 1 block per (b,h,q)) ----------------
#define KTILE 128
__global__ __launch_bounds__(256) void k_attn(const float* __restrict__ qkv,
                                              float* __restrict__ y) {
    int q = blockIdx.x, h = blockIdx.y, b = blockIdx.z;
    int tid = threadIdx.x;
    __shared__ float qv[64];
    __shared__ float s[TT];
    __shared__ float tile[KTILE][65];
    __shared__ float red[4];

    const size_t rowstride = 3 * EE;
    const size_t base = (size_t)b * TT * rowstride;
    if (tid < 64) qv[tid] = qkv[base + (size_t)q * rowstride + h * HD + tid];
    __syncthreads();

    int nk = q + 1;
    // ---- scores ----
    for (int t0 = 0; t0 < nk; t0 += KTILE) {
        int cnt = min(KTILE, nk - t0);
        for (int e = tid; e < cnt * 64; e += 256) {
            int r = e >> 6, c = e & 63;
            tile[r][c] = qkv[base + (size_t)(t0 + r) * rowstride + EE + h * HD + c];
        }
        __syncthreads();
        for (int k = tid; k < cnt; k += 256) {
            float acc = 0.f;
            #pragma unroll
            for (int d = 0; d < 64; ++d) acc = fmaf(qv[d], tile[k][d], acc);
            s[t0 + k] = acc * SCALE;
        }
        __syncthreads();
    }
    // ---- softmax over s[0..nk) ----
    float mx = -INFINITY;
    for (int k = tid; k < nk; k += 256) mx = fmaxf(mx, s[k]);
    mx = wred_max(mx);
    int lane = tid & 63, wid = tid >> 6;
    if (lane == 0) red[wid] = mx;
    __syncthreads();
    mx = fmaxf(fmaxf(red[0], red[1]), fmaxf(red[2], red[3]));
    __syncthreads();
    float lsum = 0.f;
    for (int k = tid; k < nk; k += 256) {
        float p = __expf(s[k] - mx);
        s[k] = p;
        lsum += p;
    }
    lsum = wred_sum(lsum);
    if (lane == 0) red[wid] = lsum;
    __syncthreads();
    float linv = 1.f / (red[0] + red[1] + red[2] + red[3]);
    __syncthreads();
    // ---- y = P @ V ----
    int d = tid & 63, g = tid >> 6;   // 4 k-groups of 64 dims
    float acc = 0.f;
    for (int t0 = 0; t0 < nk; t0 += KTILE) {
        int cnt = min(KTILE, nk - t0);
        for (int e = tid; e < cnt * 64; e += 256) {
            int r = e >> 6, c = e & 63;
            tile[r][c] = qkv[base + (size_t)(t0 + r) * rowstride + 2 * EE + h * HD + c];
        }
        __syncthreads();
        for (int k = g; k < cnt; k += 4)
            acc = fmaf(s[t0 + k], tile[k][d], acc);
        __syncthreads();
    }
    float* flat = &tile[0][0];
    flat[g * 64 + d] = acc;
    __syncthreads();
    if (tid < 64) {
        float r = flat[tid] + flat[64 + tid] + flat[128 + tid] + flat[192 + tid];
        y[(size_t)(b * TT + q) * EE + h * HD + tid] = r * linv;
    }
}

// ---------------- launch ----------------
extern "C" void kernel_launch(void* const* d_in, const int* in_sizes, int n_in,
                              void* d_out, int out_size, void* d_ws, size_t ws_size,
                              hipStream_t stream) {
    const int*   idx    = (const int*)  d_in[0];
    const float* wte    = (const float*)d_in[1];
    const float* wpe    = (const float*)d_in[2];
    const float* ln1_w  = (const float*)d_in[3];
    const float* ln1_b  = (const float*)d_in[4];
    const float* attn_w = (const float*)d_in[5];
    const float* attn_b = (const float*)d_in[6];
    const float* atp_w  = (const float*)d_in[7];
    const float* atp_b  = (const float*)d_in[8];
    const float* ln2_w  = (const float*)d_in[9];
    const float* ln2_b  = (const float*)d_in[10];
    const float* fc_w   = (const float*)d_in[11];
    const float* fc_b   = (const float*)d_in[12];
    const float* pr_w   = (const float*)d_in[13];
    const float* pr_b   = (const float*)d_in[14];
    const float* lnf_w  = (const float*)d_in[15];
    const float* lnf_b  = (const float*)d_in[16];
    float* out = (float*)d_out;

    float* ws = (float*)d_ws;
    float* x    = ws;                    // M*E
    float* h    = x    + (size_t)MM * EE;
    float* qkv  = h    + (size_t)MM * EE;          // M*3E
    float* y    = qkv  + (size_t)MM * 3 * EE;      // M*E
    float* mlp  = y    + (size_t)MM * EE;          // M*4E

    k_embed<<<MM, 256, 0, stream>>>(idx, wte, wpe, x);

    for (int i = 0; i < LL; ++i) {
        k_ln<<<MM, 256, 0, stream>>>(x, ln1_w + i * EE, ln1_b + i * EE, h);
        k_gemm<false, 0><<<dim3(36, 32), 256, 0, stream>>>(
            h, attn_w + (size_t)i * EE * 3 * EE, attn_b + i * 3 * EE, nullptr,
            qkv, MM, 3 * EE, EE);
        k_attn<<<dim3(TT, HH, BB), 256, 0, stream>>>(qkv, y);
        k_gemm<false, 2><<<dim3(12, 32), 256, 0, stream>>>(
            y, atp_w + (size_t)i * EE * EE, atp_b + i * EE, x,
            x, MM, EE, EE);
        k_ln<<<MM, 256, 0, stream>>>(x, ln2_w + i * EE, ln2_b + i * EE, h);
        k_gemm<false, 1><<<dim3(48, 32), 256, 0, stream>>>(
            h, fc_w + (size_t)i * EE * 4 * EE, fc_b + i * 4 * EE, nullptr,
            mlp, MM, 4 * EE, EE);
        k_gemm<false, 2><<<dim3(12, 32), 256, 0, stream>>>(
            mlp, pr_w + (size_t)i * 4 * EE * EE, pr_b + i * EE, x,
            x, MM, EE, 4 * EE);
    }

    k_ln<<<MM, 256, 0, stream>>>(x, lnf_w, lnf_b, h);
    k_gemm<true, 0><<<dim3((VV + 63) / 64, 32), 256, 0, stream>>>(
        h, wte, nullptr, nullptr, out, MM, VV, EE);
}